// Round 1
// baseline (666.608 us; speedup 1.0000x reference)
//
#include <hip/hip_runtime.h>
#include <cstdint>
#include <cstddef>

#define B_N  8192
#define FEAT 1024
#define PART 6
#define DC   128
#define OUTC 512

typedef __bf16 bf16;
typedef bf16 bf16x8 __attribute__((ext_vector_type(8)));
typedef bf16 bf16x2 __attribute__((ext_vector_type(2)));
typedef float f32x4 __attribute__((ext_vector_type(4)));

__device__ __forceinline__ void gload16(const bf16* g, bf16* l) {
  __builtin_amdgcn_global_load_lds(
      (const __attribute__((address_space(1))) void*)g,
      (__attribute__((address_space(3))) void*)l, 16, 0, 0);
}

// ---------- prep kernels ----------
__global__ void k_f2b(const float* __restrict__ s, bf16* __restrict__ d, int n) {
  int i = blockIdx.x * 256 + threadIdx.x;
  if (i < n) d[i] = (bf16)s[i];
}

__global__ void k_bn(const float* __restrict__ g, const float* __restrict__ be,
                     const float* __restrict__ m, const float* __restrict__ v,
                     float* __restrict__ sc, float* __restrict__ sh) {
  int i = blockIdx.x * 256 + threadIdx.x;
  if (i < PART * FEAT) {
    float inv = 1.0f / sqrtf(v[i] + 1e-5f);
    float s = g[i] * inv;
    sc[i] = s;
    sh[i] = be[i] - m[i] * s;
  }
}

// x [B,1024,6] f32 -> xT [6][B][1024] bf16. Each thread: one (b, c0..c0+1) pair.
__global__ void k_transpose_x(const float* __restrict__ x, bf16* __restrict__ xT) {
  int t = blockIdx.x * 256 + threadIdx.x;     // [0, 8192*512)
  int b = t >> 9;
  int c0 = (t & 511) << 1;
  const float4* src = (const float4*)(x + ((size_t)b * FEAT + c0) * PART);
  float4 v0 = src[0], v1 = src[1], v2 = src[2];
  float e[12] = {v0.x, v0.y, v0.z, v0.w, v1.x, v1.y, v1.z, v1.w, v2.x, v2.y, v2.z, v2.w};
#pragma unroll
  for (int p = 0; p < PART; ++p) {
    bf16x2 w; w.x = (bf16)e[p]; w.y = (bf16)e[6 + p];
    *(bf16x2*)(xT + ((size_t)p * B_N + b) * FEAT + c0) = w;
  }
}

// ---------- tiled MFMA GEMM: C[M,N] = A[M,K] @ W[N,K]^T, per plane z ----------
// BM=BN=128, BK=64, 256 thr (4 waves 2x2), XOR-8 swizzled LDS, global_load_lds x16B.
// EPI 0: lrelu -> f32 Fout[z][row][N]      (GEMM1: ps/cs, z: 0-5 ps, 6-11 cs, A plane z%6)
// EPI 1: BN+lrelu+resid -> bf16 Bout       (GEMM2)
// EPI 2: raw f32 Fout                      (GEMM3)
template <int EPI, int K, int N>
__global__ __launch_bounds__(256) void k_gemm(
    const bf16* __restrict__ Abase, const bf16* __restrict__ Wbase,
    float* __restrict__ Fout, bf16* __restrict__ Bout,
    const float* __restrict__ bnsc, const float* __restrict__ bnsh,
    const bf16* __restrict__ resid) {
  __shared__ bf16 As[128 * 64];
  __shared__ bf16 Ws[128 * 64];
  const int tid = threadIdx.x;
  const int wv = tid >> 6, lane = tid & 63;
  const int wr = wv >> 1, wc = wv & 1;
  const int l = lane & 15, hh = lane >> 4;
  const int tm = blockIdx.x, tn = blockIdx.y, z = blockIdx.z;

  int ap = (EPI == 0) ? (z < PART ? z : z - PART) : z;
  const bf16* A = Abase + (size_t)ap * B_N * K + (size_t)tm * 128 * K;
  const bf16* W = Wbase + (size_t)z * N * K + (size_t)tn * 128 * K;

  f32x4 acc[4][4] = {};

  for (int kt = 0; kt < K / 64; ++kt) {
    __syncthreads();
#pragma unroll
    for (int it = 0; it < 4; ++it) {
      int s = it * 256 + wv * 64 + lane;       // LDS 16B-slot (linear)
      int r = s >> 3;
      int c = (s & 7) ^ (r & 7);               // pre-swizzled global source chunk
      gload16(A + (size_t)r * K + kt * 64 + c * 8, &As[(it * 256 + wv * 64) * 8]);
      gload16(W + (size_t)r * K + kt * 64 + c * 8, &Ws[(it * 256 + wv * 64) * 8]);
    }
    asm volatile("s_waitcnt vmcnt(0)" ::: "memory");
    __syncthreads();
#pragma unroll
    for (int kk = 0; kk < 2; ++kk) {
      bf16x8 af[4], wf[4];
#pragma unroll
      for (int mi = 0; mi < 4; ++mi) {
        int row = wr * 64 + mi * 16 + l;
        int c = (kk * 4 + hh) ^ (row & 7);     // swizzled read
        af[mi] = *(const bf16x8*)&As[row * 64 + c * 8];
      }
#pragma unroll
      for (int ni = 0; ni < 4; ++ni) {
        int row = wc * 64 + ni * 16 + l;
        int c = (kk * 4 + hh) ^ (row & 7);
        wf[ni] = *(const bf16x8*)&Ws[row * 64 + c * 8];
      }
#pragma unroll
      for (int mi = 0; mi < 4; ++mi)
#pragma unroll
        for (int ni = 0; ni < 4; ++ni)
          acc[mi][ni] = __builtin_amdgcn_mfma_f32_16x16x32_bf16(af[mi], wf[ni], acc[mi][ni], 0, 0, 0);
    }
  }

#pragma unroll
  for (int mi = 0; mi < 4; ++mi)
#pragma unroll
    for (int ni = 0; ni < 4; ++ni)
#pragma unroll
      for (int r = 0; r < 4; ++r) {
        int row = tm * 128 + wr * 64 + mi * 16 + hh * 4 + r;
        int col = tn * 128 + wc * 64 + ni * 16 + l;
        float v = acc[mi][ni][r];
        if constexpr (EPI == 0) {
          v = v >= 0.f ? v : 0.25f * v;
          Fout[(size_t)z * B_N * N + (size_t)row * N + col] = v;
        } else if constexpr (EPI == 1) {
          v = v * bnsc[z * N + col] + bnsh[z * N + col];
          v = v >= 0.f ? v : 0.25f * v;
          v += (float)resid[((size_t)z * B_N + row) * N + col];
          Bout[((size_t)z * B_N + row) * N + col] = (bf16)v;
        } else {
          Fout[((size_t)z * B_N + row) * N + col] = v;
        }
      }
}

// ---------- attention: l2norm + 6x6 att + softmax(dim=p) + emb_att ----------
// 1 wave per b; lane holds k = {2*lane, 2*lane+1}.
__global__ __launch_bounds__(256) void k_att(const float* __restrict__ ps,
                                             const float* __restrict__ cs,
                                             bf16* __restrict__ embT) {
  int wv = threadIdx.x >> 6, lane = threadIdx.x & 63;
  int b = blockIdx.x * 4 + wv;
  float p0[6], p1[6], c0[6], c1[6];
#pragma unroll
  for (int p = 0; p < 6; ++p) {
    float2 v = *(const float2*)(ps + ((size_t)p * B_N + b) * DC + 2 * lane);
    p0[p] = v.x; p1[p] = v.y;
    float2 u = *(const float2*)(cs + ((size_t)p * B_N + b) * DC + 2 * lane);
    c0[p] = u.x; c1[p] = u.y;
  }
  float red[48];
#pragma unroll
  for (int p = 0; p < 6; ++p) {
    red[p] = p0[p] * p0[p] + p1[p] * p1[p];
    red[6 + p] = c0[p] * c0[p] + c1[p] * c1[p];
  }
#pragma unroll
  for (int p = 0; p < 6; ++p)
#pragma unroll
    for (int q = 0; q < 6; ++q)
      red[12 + p * 6 + q] = p0[p] * c0[q] + p1[p] * c1[q];
#pragma unroll
  for (int m = 1; m < 64; m <<= 1)
#pragma unroll
    for (int i = 0; i < 48; ++i)
      red[i] += __shfl_xor(red[i], m, 64);

  float inp[6], inc[6];
#pragma unroll
  for (int p = 0; p < 6; ++p) {
    inp[p] = 1.f / (sqrtf(red[p]) + 1e-8f);
    inc[p] = 1.f / (sqrtf(red[6 + p]) + 1e-8f);
  }
  float att[6][6];
#pragma unroll
  for (int p = 0; p < 6; ++p)
#pragma unroll
    for (int q = 0; q < 6; ++q)
      att[p][q] = red[12 + p * 6 + q] * inp[p] * inc[q] + (p == q ? -1000000.f : 0.f);
  // softmax over p, per column q
#pragma unroll
  for (int q = 0; q < 6; ++q) {
    float mx = att[0][q];
#pragma unroll
    for (int p = 1; p < 6; ++p) mx = fmaxf(mx, att[p][q]);
    float e[6], s = 0.f;
#pragma unroll
    for (int p = 0; p < 6; ++p) { e[p] = expf(att[p][q] - mx); s += e[p]; }
    float is = 1.f / s;
#pragma unroll
    for (int p = 0; p < 6; ++p) att[p][q] = e[p] * is;
  }
#pragma unroll
  for (int q = 0; q < 6; ++q) {
    float e0 = 0.f, e1 = 0.f;
#pragma unroll
    for (int p = 0; p < 6; ++p) {
      float a = att[p][q] * inp[p];
      e0 += p0[p] * a; e1 += p1[p] * a;
    }
    bf16x2 w; w.x = (bf16)e0; w.y = (bf16)e1;
    *(bf16x2*)(embT + ((size_t)q * B_N + b) * DC + 2 * lane) = w;
  }
}

// outT [6][B][512] f32 -> out [B,512,6] f32
__global__ void k_transpose_out(const float* __restrict__ oT, float* __restrict__ out) {
  int t = blockIdx.x * 256 + threadIdx.x;     // [0, 8192*256)
  int b = t >> 8;
  int o0 = (t & 255) << 1;
  float a[6], c[6];
#pragma unroll
  for (int p = 0; p < 6; ++p) {
    float2 v = *(const float2*)(oT + ((size_t)p * B_N + b) * OUTC + o0);
    a[p] = v.x; c[p] = v.y;
  }
  float* dst = out + ((size_t)b * OUTC + o0) * PART;
  float4 w0 = {a[0], a[1], a[2], a[3]};
  float4 w1 = {a[4], a[5], c[0], c[1]};
  float4 w2 = {c[2], c[3], c[4], c[5]};
  ((float4*)dst)[0] = w0; ((float4*)dst)[1] = w1; ((float4*)dst)[2] = w2;
}

extern "C" void kernel_launch(void* const* d_in, const int* in_sizes, int n_in,
                              void* d_out, int out_size, void* d_ws, size_t ws_size,
                              hipStream_t stream) {
  const float* x    = (const float*)d_in[0];
  const float* w_ps = (const float*)d_in[1];
  const float* w_cs = (const float*)d_in[2];
  const float* w_up = (const float*)d_in[3];
  const float* gam  = (const float*)d_in[4];
  const float* bet  = (const float*)d_in[5];
  const float* mea  = (const float*)d_in[6];
  const float* var  = (const float*)d_in[7];
  const float* w_la = (const float*)d_in[8];

  char* ws = (char*)d_ws;
  size_t off = 0;
  auto alloc = [&](size_t bytes) { void* p = ws + off; off += (bytes + 255) & ~(size_t)255; return p; };

  bf16* xT    = (bf16*)alloc((size_t)PART * B_N * FEAT * 2);     // 100.7 MB (reused as outT)
  bf16* wpsb  = (bf16*)alloc((size_t)2 * PART * DC * FEAT * 2);  // ps planes 0-5, cs planes 6-11
  bf16* wupb  = (bf16*)alloc((size_t)PART * FEAT * DC * 2);
  bf16* wlab  = (bf16*)alloc((size_t)PART * OUTC * FEAT * 2);
  float* bnsc = (float*)alloc((size_t)PART * FEAT * 4);
  float* bnsh = (float*)alloc((size_t)PART * FEAT * 4);
  float* psb  = (float*)alloc((size_t)2 * PART * B_N * DC * 4);  // ps planes 0-5, cs planes 6-11
  bf16* embT  = (bf16*)alloc((size_t)PART * B_N * DC * 2);
  bf16* emb2T = (bf16*)alloc((size_t)PART * B_N * FEAT * 2);     // total ~263 MB
  float* outT = (float*)xT;                                      // alias: xT dead after GEMM2

  const int nw = PART * DC * FEAT;    // 786432
  const int nl = PART * OUTC * FEAT;  // 3145728
  k_f2b<<<(nw + 255) / 256, 256, 0, stream>>>(w_ps, wpsb, nw);
  k_f2b<<<(nw + 255) / 256, 256, 0, stream>>>(w_cs, wpsb + nw, nw);
  k_f2b<<<(nw + 255) / 256, 256, 0, stream>>>(w_up, wupb, nw);
  k_f2b<<<(nl + 255) / 256, 256, 0, stream>>>(w_la, wlab, nl);
  k_bn<<<(PART * FEAT + 255) / 256, 256, 0, stream>>>(gam, bet, mea, var, bnsc, bnsh);
  k_transpose_x<<<B_N * 512 / 256, 256, 0, stream>>>(x, xT);

  // GEMM1: ps/cs = lrelu(x_p @ Wps/Wcs^T), 12 planes
  k_gemm<0, FEAT, DC><<<dim3(64, 1, 12), 256, 0, stream>>>(
      xT, wpsb, psb, nullptr, nullptr, nullptr, nullptr);
  // attention
  k_att<<<B_N / 4, 256, 0, stream>>>(psb, psb + (size_t)PART * B_N * DC, embT);
  // GEMM2: emb2 = x + lrelu(BN(emb_att @ Wup^T))
  k_gemm<1, DC, FEAT><<<dim3(64, 8, 6), 256, 0, stream>>>(
      embT, wupb, nullptr, emb2T, bnsc, bnsh, xT);
  // GEMM3: outT = emb2 @ Wla^T
  k_gemm<2, FEAT, OUTC><<<dim3(64, 4, 6), 256, 0, stream>>>(
      emb2T, wlab, outT, nullptr, nullptr, nullptr, nullptr);
  k_transpose_out<<<B_N * 256 / 256, 256, 0, stream>>>(outT, (float*)d_out);
}

// Round 2
// 615.852 us; speedup vs baseline: 1.0824x; 1.0824x over previous
//
#include <hip/hip_runtime.h>
#include <cstdint>
#include <cstddef>

#define B_N  8192
#define FEAT 1024
#define PART 6
#define DC   128
#define OUTC 512

typedef __bf16 bf16;
typedef bf16 bf16x8 __attribute__((ext_vector_type(8)));
typedef bf16 bf16x2 __attribute__((ext_vector_type(2)));
typedef float f32x4 __attribute__((ext_vector_type(4)));

__device__ __forceinline__ void gload16(const bf16* g, bf16* l) {
  __builtin_amdgcn_global_load_lds(
      (const __attribute__((address_space(1))) void*)g,
      (__attribute__((address_space(3))) void*)l, 16, 0, 0);
}

// ---------- fused prep: weight bf16 casts (ps/cs interleaved) + BN fold ----------
__global__ void k_prep(const float* __restrict__ w_ps, const float* __restrict__ w_cs,
                       const float* __restrict__ w_up, const float* __restrict__ w_la,
                       const float* __restrict__ g, const float* __restrict__ be,
                       const float* __restrict__ m, const float* __restrict__ v,
                       bf16* __restrict__ wpsb, bf16* __restrict__ wupb,
                       bf16* __restrict__ wlab, float* __restrict__ bnsc,
                       float* __restrict__ bnsh) {
  int i = blockIdx.x * 256 + threadIdx.x;
  const int NW = PART * DC * FEAT;    // 786432
  const int NL = PART * OUTC * FEAT;  // 3145728
  if (i < NW) {
    int z = i / (DC * FEAT), r = i % (DC * FEAT);
    // wpsb viewed as [6][256][1024]: rows 0-127 = w_ps[z], 128-255 = w_cs[z]
    wpsb[(size_t)(2 * z) * DC * FEAT + r] = (bf16)w_ps[i];
    wpsb[(size_t)(2 * z + 1) * DC * FEAT + r] = (bf16)w_cs[i];
    wupb[i] = (bf16)w_up[i];
  }
  if (i < NL) wlab[i] = (bf16)w_la[i];
  if (i < PART * FEAT) {
    float inv = 1.0f / sqrtf(v[i] + 1e-5f);
    float s = g[i] * inv;
    bnsc[i] = s;
    bnsh[i] = be[i] - m[i] * s;
  }
}

// x [B,1024,6] f32 -> xT [6][B][1024] bf16
__global__ void k_transpose_x(const float* __restrict__ x, bf16* __restrict__ xT) {
  int t = blockIdx.x * 256 + threadIdx.x;     // [0, 8192*512)
  int b = t >> 9;
  int c0 = (t & 511) << 1;
  const float4* src = (const float4*)(x + ((size_t)b * FEAT + c0) * PART);
  float4 v0 = src[0], v1 = src[1], v2 = src[2];
  float e[12] = {v0.x, v0.y, v0.z, v0.w, v1.x, v1.y, v1.z, v1.w, v2.x, v2.y, v2.z, v2.w};
#pragma unroll
  for (int p = 0; p < PART; ++p) {
    bf16x2 w; w.x = (bf16)e[p]; w.y = (bf16)e[6 + p];
    *(bf16x2*)(xT + ((size_t)p * B_N + b) * FEAT + c0) = w;
  }
}

// ---------- tiled MFMA GEMM: Out[z][M,N] = A[z][M,K] @ W[z][N,K]^T, bf16 out ----------
// BM=BN=128, BK=64, 4 waves 2x2, XOR-8 swizzle both sides, global_load_lds x16B.
// 1-D grid, XCD-chunked swizzle (nwg%8==0), tn-fastest for A-tile L2 reuse.
// EPI 0: lrelu            (GEMM1: ps|cs merged, N=256)
// EPI 1: BN+lrelu+resid   (GEMM2)
// EPI 2: raw              (GEMM3)
template <int EPI, int K, int N, int TM, int TN, int NZ>
__global__ __launch_bounds__(256) void k_gemm(
    const bf16* __restrict__ Abase, const bf16* __restrict__ Wbase,
    bf16* __restrict__ Out,
    const float* __restrict__ bnsc, const float* __restrict__ bnsh,
    const bf16* __restrict__ resid) {
  __shared__ bf16 As[128 * 64];
  __shared__ bf16 Ws[128 * 64];
  const int tid = threadIdx.x;
  const int wv = tid >> 6, lane = tid & 63;
  const int wr = wv >> 1, wc = wv & 1;
  const int l = lane & 15, hh = lane >> 4;

  // XCD-chunked bijective swizzle: nwg = TM*TN*NZ, multiple of 8.
  constexpr int NWG = TM * TN * NZ;
  constexpr int QC = NWG / 8;
  int bid = blockIdx.x;
  int lid = (bid & 7) * QC + (bid >> 3);
  int tn = lid % TN;
  int tm = (lid / TN) % TM;
  int z = lid / (TN * TM);

  const bf16* A = Abase + (size_t)z * B_N * K + (size_t)tm * 128 * K;
  const bf16* W = Wbase + (size_t)z * N * K + (size_t)tn * 128 * K;

  f32x4 acc[4][4] = {};

  for (int kt = 0; kt < K / 64; ++kt) {
    __syncthreads();
#pragma unroll
    for (int it = 0; it < 4; ++it) {
      int s = it * 256 + wv * 64 + lane;       // LDS 16B-slot (linear dest)
      int r = s >> 3;
      int c = (s & 7) ^ (r & 7);               // pre-swizzled global source chunk
      gload16(A + (size_t)r * K + kt * 64 + c * 8, &As[(it * 256 + wv * 64) * 8]);
      gload16(W + (size_t)r * K + kt * 64 + c * 8, &Ws[(it * 256 + wv * 64) * 8]);
    }
    asm volatile("s_waitcnt vmcnt(0)" ::: "memory");
    __syncthreads();
#pragma unroll
    for (int kk = 0; kk < 2; ++kk) {
      bf16x8 af[4], wf[4];
#pragma unroll
      for (int mi = 0; mi < 4; ++mi) {
        int row = wr * 64 + mi * 16 + l;
        int c = (kk * 4 + hh) ^ (row & 7);     // swizzled read
        af[mi] = *(const bf16x8*)&As[row * 64 + c * 8];
      }
#pragma unroll
      for (int ni = 0; ni < 4; ++ni) {
        int row = wc * 64 + ni * 16 + l;
        int c = (kk * 4 + hh) ^ (row & 7);
        wf[ni] = *(const bf16x8*)&Ws[row * 64 + c * 8];
      }
#pragma unroll
      for (int mi = 0; mi < 4; ++mi)
#pragma unroll
        for (int ni = 0; ni < 4; ++ni)
          acc[mi][ni] = __builtin_amdgcn_mfma_f32_16x16x32_bf16(af[mi], wf[ni], acc[mi][ni], 0, 0, 0);
    }
  }

#pragma unroll
  for (int mi = 0; mi < 4; ++mi)
#pragma unroll
    for (int ni = 0; ni < 4; ++ni)
#pragma unroll
      for (int r = 0; r < 4; ++r) {
        int row = tm * 128 + wr * 64 + mi * 16 + hh * 4 + r;
        int col = tn * 128 + wc * 64 + ni * 16 + l;
        float v = acc[mi][ni][r];
        if constexpr (EPI == 0) {
          v = v >= 0.f ? v : 0.25f * v;
        } else if constexpr (EPI == 1) {
          v = v * bnsc[z * N + col] + bnsh[z * N + col];
          v = v >= 0.f ? v : 0.25f * v;
          v += (float)resid[((size_t)z * B_N + row) * N + col];
        }
        Out[((size_t)z * B_N + row) * N + col] = (bf16)v;
      }
}

// ---------- attention: l2norm + 6x6 att + softmax(dim=p) + emb_att ----------
// psb bf16 [6][B][256]: cols 0-127 = ps, 128-255 = cs. 1 wave per b.
__global__ __launch_bounds__(256) void k_att(const bf16* __restrict__ psb,
                                             bf16* __restrict__ embT) {
  int wv = threadIdx.x >> 6, lane = threadIdx.x & 63;
  int b = blockIdx.x * 4 + wv;
  float p0[6], p1[6], c0[6], c1[6];
#pragma unroll
  for (int p = 0; p < 6; ++p) {
    const bf16* base = psb + ((size_t)p * B_N + b) * 256;
    bf16x2 v = *(const bf16x2*)(base + 2 * lane);
    p0[p] = (float)v.x; p1[p] = (float)v.y;
    bf16x2 u = *(const bf16x2*)(base + 128 + 2 * lane);
    c0[p] = (float)u.x; c1[p] = (float)u.y;
  }
  float red[48];
#pragma unroll
  for (int p = 0; p < 6; ++p) {
    red[p] = p0[p] * p0[p] + p1[p] * p1[p];
    red[6 + p] = c0[p] * c0[p] + c1[p] * c1[p];
  }
#pragma unroll
  for (int p = 0; p < 6; ++p)
#pragma unroll
    for (int q = 0; q < 6; ++q)
      red[12 + p * 6 + q] = p0[p] * c0[q] + p1[p] * c1[q];
#pragma unroll
  for (int m = 1; m < 64; m <<= 1)
#pragma unroll
    for (int i = 0; i < 48; ++i)
      red[i] += __shfl_xor(red[i], m, 64);

  float inp[6], inc[6];
#pragma unroll
  for (int p = 0; p < 6; ++p) {
    inp[p] = 1.f / (sqrtf(red[p]) + 1e-8f);
    inc[p] = 1.f / (sqrtf(red[6 + p]) + 1e-8f);
  }
  float att[6][6];
#pragma unroll
  for (int p = 0; p < 6; ++p)
#pragma unroll
    for (int q = 0; q < 6; ++q)
      att[p][q] = red[12 + p * 6 + q] * inp[p] * inc[q] + (p == q ? -1000000.f : 0.f);
#pragma unroll
  for (int q = 0; q < 6; ++q) {
    float mx = att[0][q];
#pragma unroll
    for (int p = 1; p < 6; ++p) mx = fmaxf(mx, att[p][q]);
    float e[6], s = 0.f;
#pragma unroll
    for (int p = 0; p < 6; ++p) { e[p] = expf(att[p][q] - mx); s += e[p]; }
    float is = 1.f / s;
#pragma unroll
    for (int p = 0; p < 6; ++p) att[p][q] = e[p] * is;
  }
#pragma unroll
  for (int q = 0; q < 6; ++q) {
    float e0 = 0.f, e1 = 0.f;
#pragma unroll
    for (int p = 0; p < 6; ++p) {
      float a = att[p][q] * inp[p];
      e0 += p0[p] * a; e1 += p1[p] * a;
    }
    bf16x2 w; w.x = (bf16)e0; w.y = (bf16)e1;
    *(bf16x2*)(embT + ((size_t)q * B_N + b) * DC + 2 * lane) = w;
  }
}

// outT [6][B][512] bf16 -> out [B,512,6] f32
__global__ void k_transpose_out(const bf16* __restrict__ oT, float* __restrict__ out) {
  int t = blockIdx.x * 256 + threadIdx.x;     // [0, 8192*256)
  int b = t >> 8;
  int o0 = (t & 255) << 1;
  float a[6], c[6];
#pragma unroll
  for (int p = 0; p < 6; ++p) {
    bf16x2 v = *(const bf16x2*)(oT + ((size_t)p * B_N + b) * OUTC + o0);
    a[p] = (float)v.x; c[p] = (float)v.y;
  }
  float* dst = out + ((size_t)b * OUTC + o0) * PART;
  float4 w0 = {a[0], a[1], a[2], a[3]};
  float4 w1 = {a[4], a[5], c[0], c[1]};
  float4 w2 = {c[2], c[3], c[4], c[5]};
  ((float4*)dst)[0] = w0; ((float4*)dst)[1] = w1; ((float4*)dst)[2] = w2;
}

extern "C" void kernel_launch(void* const* d_in, const int* in_sizes, int n_in,
                              void* d_out, int out_size, void* d_ws, size_t ws_size,
                              hipStream_t stream) {
  const float* x    = (const float*)d_in[0];
  const float* w_ps = (const float*)d_in[1];
  const float* w_cs = (const float*)d_in[2];
  const float* w_up = (const float*)d_in[3];
  const float* gam  = (const float*)d_in[4];
  const float* bet  = (const float*)d_in[5];
  const float* mea  = (const float*)d_in[6];
  const float* var  = (const float*)d_in[7];
  const float* w_la = (const float*)d_in[8];

  char* ws = (char*)d_ws;
  size_t off = 0;
  auto alloc = [&](size_t bytes) { void* p = ws + off; off += (bytes + 255) & ~(size_t)255; return p; };

  bf16* xT    = (bf16*)alloc((size_t)PART * B_N * FEAT * 2);       // 100.7 MB (reused as outT)
  bf16* wpsb  = (bf16*)alloc((size_t)PART * 256 * FEAT * 2);       // [6][256][1024] ps|cs
  bf16* wupb  = (bf16*)alloc((size_t)PART * FEAT * DC * 2);
  bf16* wlab  = (bf16*)alloc((size_t)PART * OUTC * FEAT * 2);
  float* bnsc = (float*)alloc((size_t)PART * FEAT * 4);
  float* bnsh = (float*)alloc((size_t)PART * FEAT * 4);
  bf16* psb   = (bf16*)alloc((size_t)PART * B_N * 256 * 2);        // 25.2 MB
  bf16* embT  = (bf16*)alloc((size_t)PART * B_N * DC * 2);
  bf16* emb2T = (bf16*)alloc((size_t)PART * B_N * FEAT * 2);
  bf16* outT  = xT;                                                // alias: xT dead after GEMM2

  k_prep<<<(PART * OUTC * FEAT + 255) / 256, 256, 0, stream>>>(
      w_ps, w_cs, w_up, w_la, gam, bet, mea, var, wpsb, wupb, wlab, bnsc, bnsh);
  k_transpose_x<<<B_N * 512 / 256, 256, 0, stream>>>(x, xT);

  // GEMM1: [ps|cs] = lrelu(x_p @ [Wps;Wcs]^T), N=256, A read once
  k_gemm<0, FEAT, 256, 64, 2, 6><<<768, 256, 0, stream>>>(
      xT, wpsb, psb, nullptr, nullptr, nullptr);
  // attention
  k_att<<<B_N / 4, 256, 0, stream>>>(psb, embT);
  // GEMM2: emb2 = x + lrelu(BN(emb_att @ Wup^T))
  k_gemm<1, DC, FEAT, 64, 8, 6><<<3072, 256, 0, stream>>>(
      embT, wupb, emb2T, bnsc, bnsh, xT);
  // GEMM3: outT = emb2 @ Wla^T
  k_gemm<2, FEAT, OUTC, 64, 4, 6><<<1536, 256, 0, stream>>>(
      emb2T, wlab, outT, nullptr, nullptr, nullptr);
  k_transpose_out<<<B_N * 256 / 256, 256, 0, stream>>>(outT, (float*)d_out);
}